// Round 2
// baseline (212.614 us; speedup 1.0000x reference)
//
#include <hip/hip_runtime.h>
#include <climits>

#define HH 512
#define WW 512
#define BN 32
#define NCH 3
#define MS 256

// ---------------- init: seed the per-batch bbox atomics in workspace --------
__global__ void init_bbox(int* __restrict__ bbox) {
    int i = threadIdx.x;
    if (i < BN) {
        bbox[i * 4 + 0] = INT_MAX;  // r0 (min row)
        bbox[i * 4 + 1] = -1;       // r1 (max row)
        bbox[i * 4 + 2] = INT_MAX;  // c0 (min col)
        bbox[i * 4 + 3] = -1;       // c1 (max col)
    }
}

// ---------------- bbox: per-batch min/max row/col of nonzero mask -----------
// input1 shape (32, 4, 512, 512); mask = channel 3.
__global__ __launch_bounds__(256) void bbox_kernel(const float* __restrict__ in1,
                                                   int* __restrict__ bbox) {
    const int b = blockIdx.y;
    const float4* w =
        reinterpret_cast<const float4*>(in1 + ((size_t)b * 4 + 3) * (HH * WW));
    const int nvec = HH * WW / 4;  // 65536 float4; rows never straddled (512%4==0)

    int r0 = INT_MAX, r1 = -1, c0 = INT_MAX, c1 = -1;
    for (int i = blockIdx.x * blockDim.x + threadIdx.x; i < nvec;
         i += gridDim.x * blockDim.x) {
        float4 v = w[i];
        if (v.x != 0.f || v.y != 0.f || v.z != 0.f || v.w != 0.f) {
            int e = i * 4;
            int row = e >> 9;      // /512
            int col = e & 511;     // %512
            r0 = min(r0, row);
            r1 = max(r1, row);
            if (v.x != 0.f) { c0 = min(c0, col);     c1 = max(c1, col);     }
            if (v.y != 0.f) { c0 = min(c0, col + 1); c1 = max(c1, col + 1); }
            if (v.z != 0.f) { c0 = min(c0, col + 2); c1 = max(c1, col + 2); }
            if (v.w != 0.f) { c0 = min(c0, col + 3); c1 = max(c1, col + 3); }
        }
    }

    // wave-64 butterfly reduce (no divergence cost, density-independent)
#pragma unroll
    for (int m = 1; m < 64; m <<= 1) {
        r0 = min(r0, __shfl_xor(r0, m, 64));
        r1 = max(r1, __shfl_xor(r1, m, 64));
        c0 = min(c0, __shfl_xor(c0, m, 64));
        c1 = max(c1, __shfl_xor(c1, m, 64));
    }

    __shared__ int s[4];
    if (threadIdx.x == 0) { s[0] = INT_MAX; s[1] = -1; s[2] = INT_MAX; s[3] = -1; }
    __syncthreads();
    if ((threadIdx.x & 63) == 0 && r1 >= 0) {   // one set of LDS atomics per wave
        atomicMin(&s[0], r0);
        atomicMax(&s[1], r1);
        atomicMin(&s[2], c0);
        atomicMax(&s[3], c1);
    }
    __syncthreads();
    if (threadIdx.x == 0 && s[1] >= 0) {
        atomicMin(&bbox[b * 4 + 0], s[0]);
        atomicMax(&bbox[b * 4 + 1], s[1]);
        atomicMin(&bbox[b * 4 + 2], s[2]);
        atomicMax(&bbox[b * 4 + 3], s[3]);
    }
}

// ---------------- crop: gather valid region centered into 256x256 ----------
// One thread per float4 of output; output flat layout (b, ch, y, x).
__global__ __launch_bounds__(256) void crop_kernel(const float* __restrict__ in1,
                                                   const int4* __restrict__ bbox,
                                                   float4* __restrict__ out) {
    const int idx = blockIdx.x * blockDim.x + threadIdx.x;
    // total = 32*3*256*64 = 1,572,864 float4
    const int x4 = (idx & 63) << 2;       // output x of first component
    const int y  = (idx >> 6) & 255;      // output y
    const int t  = idx >> 14;             // b*3 + ch  (plane = 2^14 float4)
    const int b  = t / 3;
    const int ch = t - b * 3;

    const int4 bb = bbox[b];
    const int sides_h = bb.y - bb.x;      // r1 - r0  (>=0, <=255)
    const int sides_w = bb.w - bb.z;      // c1 - c0
    const int top  = (MS - sides_h) >> 1; // non-negative -> >>1 == floor-div
    const int left = (MS - sides_w) >> 1;

    float4 o = make_float4(0.f, 0.f, 0.f, 0.f);
    if (y >= top && y < top + sides_h) {
        const int src_y = y - top + bb.x;           // in [r0, r1) ⊂ [0,512)
        const float* row =
            in1 + (((size_t)b * 4 + ch) * HH + (size_t)src_y) * WW;
        const int sx = x4 - left + bb.z;            // src_x of component 0
        // intersect [x4, x4+4) with [left, left+sides_w)
        const int jlo = max(0, left - x4);
        const int jhi = min(4, left + sides_w - x4);
        float* op = reinterpret_cast<float*>(&o);
#pragma unroll 4
        for (int j = jlo; j < jhi; ++j) {
            // valid ⇒ src_x = x-left+c0 ∈ [c0, c1) ⊂ [0,512): no clip needed
            op[j] = row[sx + j];
        }
    }
    out[idx] = o;
}

extern "C" void kernel_launch(void* const* d_in, const int* in_sizes, int n_in,
                              void* d_out, int out_size, void* d_ws, size_t ws_size,
                              hipStream_t stream) {
    const float* in1 = (const float*)d_in[0];   // (32,4,512,512) f32
    float* out = (float*)d_out;                 // (32,3,256,256) f32
    int* bbox = (int*)d_ws;                     // 32 * int4

    init_bbox<<<1, 64, 0, stream>>>(bbox);

    dim3 g(32, BN);
    bbox_kernel<<<g, 256, 0, stream>>>(in1, bbox);

    const int total_vec4 = BN * NCH * MS * (MS / 4);  // 1,572,864
    crop_kernel<<<total_vec4 / 256, 256, 0, stream>>>(
        in1, (const int4*)bbox, (float4*)out);
}